// Round 1
// baseline (338.045 us; speedup 1.0000x reference)
//
#include <hip/hip_runtime.h>

#define FLT_MAX_F 3.402823466e38f

// tie-break matches jax.lax.top_k: higher value wins; equal values -> lower index wins
static __device__ __forceinline__ bool better(float v1, int i1, float v2, int i2) {
  return (v1 > v2) || ((v1 == v2) && (i1 < i2));
}

// kmean[h][n][e] = mean_j x[(n*32+j)*256 + h*32+e]
__global__ void kmean_kernel(const float* __restrict__ x, float* __restrict__ km) {
  const int n = blockIdx.x;        // ball
  const int t = threadIdx.x;       // h*32+e
  const float* base = x + n * 32 * 256 + t;
  float acc = 0.f;
  #pragma unroll
  for (int j = 0; j < 32; ++j) acc += base[j * 256];
  const int h = t >> 5, e = t & 31;
  km[h * (256 * 32) + n * 32 + e] = acc * (1.0f / 32.0f);
}

// one wave per (h, q) task
__global__ __launch_bounds__(256) void attn_kernel(const float* __restrict__ x,
                                                   const float* __restrict__ km,
                                                   float* __restrict__ out) {
  const int lane = threadIdx.x & 63;
  const int task = blockIdx.x * 4 + (threadIdx.x >> 6);   // 0..65535
  const int h = task >> 13;                               // consecutive blocks share head (cache locality)
  const int q = task & 8191;

  // ---- load q vector (broadcast across lanes) ----
  const float4* qp = reinterpret_cast<const float4*>(x + q * 256 + h * 32);
  float qv[32];
  #pragma unroll
  for (int o = 0; o < 8; ++o) {
    float4 f = qp[o];
    qv[4*o+0] = f.x; qv[4*o+1] = f.y; qv[4*o+2] = f.z; qv[4*o+3] = f.w;
  }

  // ---- sim logits: 4 balls per lane ----
  const float* kmh = km + h * (256 * 32);
  float lg[4];
  #pragma unroll
  for (int jj = 0; jj < 4; ++jj) {
    const int n = lane + 64 * jj;
    const float4* kp = reinterpret_cast<const float4*>(kmh + n * 32);
    float acc = 0.f;
    #pragma unroll
    for (int o = 0; o < 8; ++o) {
      float4 f = kp[o];
      acc = fmaf(qv[4*o+0], f.x, acc);
      acc = fmaf(qv[4*o+1], f.y, acc);
      acc = fmaf(qv[4*o+2], f.z, acc);
      acc = fmaf(qv[4*o+3], f.w, acc);
    }
    lg[jj] = acc * 0.0625f;   // scale = DIM^-0.5 = 1/16
  }

  // ---- per-lane top2 (with indices) ----
  float v1 = lg[0]; int i1 = lane;
  float v2 = lg[1]; int i2 = lane + 64;
  if (better(v2, i2, v1, i1)) { float tv = v1; int ti = i1; v1 = v2; i1 = i2; v2 = tv; i2 = ti; }
  #pragma unroll
  for (int jj = 2; jj < 4; ++jj) {
    float v = lg[jj]; int i = lane + 64 * jj;
    if (better(v, i, v1, i1)) { v2 = v1; i2 = i1; v1 = v; i1 = i; }
    else if (better(v, i, v2, i2)) { v2 = v; i2 = i; }
  }
  // ---- butterfly merge of sorted top2 lists ----
  #pragma unroll
  for (int m = 1; m < 64; m <<= 1) {
    float b1 = __shfl_xor(v1, m); int j1 = __shfl_xor(i1, m);
    float b2 = __shfl_xor(v2, m); int j2 = __shfl_xor(i2, m);
    if (better(b1, j1, v1, i1)) {
      float nv2; int ni2;
      if (better(v1, i1, b2, j2)) { nv2 = v1; ni2 = i1; } else { nv2 = b2; ni2 = j2; }
      v1 = b1; i1 = j1; v2 = nv2; i2 = ni2;
    } else if (better(b1, j1, v2, i2)) {
      v2 = b1; i2 = j1;
    }
  }

  // ---- softmax denominator over all 256 (v1 is the global max logit) ----
  float esum = 0.f;
  #pragma unroll
  for (int jj = 0; jj < 4; ++jj) esum += __expf(lg[jj] - v1);
  #pragma unroll
  for (int m = 1; m < 64; m <<= 1) esum += __shfl_xor(esum, m);

  const float topv1 = 1.0f / esum;              // softmax value at top-1
  const float topv2 = __expf(v2 - v1) / esum;   // softmax value at top-2
  const bool msk1 = topv1 > 1e-10f;
  const bool msk2 = topv2 > 1e-10f;

  // ---- attention over 64 gathered keys: lane s = (t2*32 + jm) ----
  const int t2 = lane >> 5;          // which topk slot
  const int jm = lane & 31;          // member within ball / output element
  const int ball = t2 ? i2 : i1;
  const bool valid = t2 ? msk2 : msk1;
  const int row = ball * 32 + jm;

  const float4* kp = reinterpret_cast<const float4*>(x + row * 256 + h * 32);
  float sdot = 0.f;
  #pragma unroll
  for (int o = 0; o < 8; ++o) {
    float4 f = kp[o];
    sdot = fmaf(qv[4*o+0], f.x, sdot);
    sdot = fmaf(qv[4*o+1], f.y, sdot);
    sdot = fmaf(qv[4*o+2], f.z, sdot);
    sdot = fmaf(qv[4*o+3], f.w, sdot);
  }
  float fs = valid ? sdot * 0.0625f : -FLT_MAX_F;
  float mx = fs;
  #pragma unroll
  for (int m = 1; m < 64; m <<= 1) mx = fmaxf(mx, __shfl_xor(mx, m));
  float p = valid ? __expf(fs - mx) : 0.f;
  float psum = p;
  #pragma unroll
  for (int m = 1; m < 64; m <<= 1) psum += __shfl_xor(psum, m);

  // ---- weighted sum out[e] = sum_s p_s * v_s[e] ----
  // lane (t2=0, jm=e) sums s=0..31 (ball i1); lane (t2=1, jm=e) sums s=32..63 (ball i2).
  // v rows re-read from global in transposed direction (L1-hot lines), weights via shfl.
  const int rbase = (ball * 32) * 256 + h * 32 + jm;
  float acc = 0.f;
  #pragma unroll
  for (int s2 = 0; s2 < 32; ++s2) {
    float ps = __shfl(p, t2 * 32 + s2);
    acc = fmaf(ps, x[rbase + s2 * 256], acc);
  }
  acc += __shfl_xor(acc, 32);
  if (lane < 32) out[q * 256 + h * 32 + jm] = acc / psum;
}

extern "C" void kernel_launch(void* const* d_in, const int* in_sizes, int n_in,
                              void* d_out, int out_size, void* d_ws, size_t ws_size,
                              hipStream_t stream) {
  const float* x = (const float*)d_in[0];   // (8192, 256) fp32; d_in[1] (pos) is dead code
  float* km = (float*)d_ws;                 // 8*256*32 fp32 = 256 KB scratch
  float* out = (float*)d_out;

  kmean_kernel<<<256, 256, 0, stream>>>(x, km);
  attn_kernel<<<16384, 256, 0, stream>>>(x, km, out);
}

// Round 2
// 88.436 us; speedup vs baseline: 3.8225x; 3.8225x over previous
//
#include <hip/hip_runtime.h>

#define FLT_BIG 3.402823466e38f

// tie-break matches jax.lax.top_k: higher value wins; equal values -> lower index wins
static __device__ __forceinline__ bool better(float v1, int i1, float v2, int i2) {
  return (v1 > v2) || ((v1 == v2) && (i1 < i2));
}

// km[h][n][e] = mean_j x[(n*32+j)*256 + h*32+e]
__global__ void kmean_kernel(const float* __restrict__ x, float* __restrict__ km) {
  const int n = blockIdx.x;        // ball
  const int t = threadIdx.x;       // h*32+e
  const float* base = x + n * 32 * 256 + t;
  float acc = 0.f;
  #pragma unroll
  for (int j = 0; j < 32; ++j) acc += base[j * 256];
  const int h = t >> 5, e = t & 31;
  km[h * 8192 + n * 32 + e] = acc * (1.0f / 32.0f);
}

// One block per (h, ball). Computes sim = softmax(q . kmean * scale) top-2 + mask
// for the ball's 32 queries. Thread t owns ball-column n=t of the 32x256 sim tile.
__global__ __launch_bounds__(256) void select_kernel(const float* __restrict__ x,
                                                     const float* __restrict__ km,
                                                     int2* __restrict__ sel) {
  const int h = blockIdx.x >> 8;   // consecutive blocks share head -> L2 locality on km[h]
  const int b = blockIdx.x & 255;
  const int t = threadIdx.x;

  // phase A: buf = km[h] (8192 floats, linear). phase B/C: buf = sim[32][260] (padded).
  __shared__ __align__(16) float buf[32 * 260];
  __shared__ __align__(16) float q_lds[32 * 32];
  __shared__ float4 cand[32 * 8];
  __shared__ float cesum[32 * 8];

  // ---- coalesced staging ----
  {
    const float4* src = (const float4*)(km + h * 8192);
    float4* dst = (float4*)buf;
    #pragma unroll
    for (int i = 0; i < 8; ++i) dst[i * 256 + t] = src[i * 256 + t];
  }
  {
    const int r = t >> 3, o = t & 7;   // 8 lanes per row -> full 128B row-slices per instr
    ((float4*)q_lds)[r * 8 + o] = *(const float4*)(x + (b * 32 + r) * 256 + h * 32 + o * 4);
  }
  __syncthreads();

  // km row n=t -> registers, then buf is reused for sim
  float4 kr[8];
  #pragma unroll
  for (int o = 0; o < 8; ++o) kr[o] = ((const float4*)buf)[t * 8 + o];
  __syncthreads();

  // ---- sim GEMM: 32 q x (my ball) ----
  float acc[32];
  #pragma unroll
  for (int q = 0; q < 32; ++q) {
    float a = 0.f;
    #pragma unroll
    for (int o = 0; o < 8; ++o) {
      float4 qf = ((const float4*)q_lds)[q * 8 + o];   // broadcast
      a = fmaf(kr[o].x, qf.x, a);
      a = fmaf(kr[o].y, qf.y, a);
      a = fmaf(kr[o].z, qf.z, a);
      a = fmaf(kr[o].w, qf.w, a);
    }
    acc[q] = a * 0.0625f;   // scale = 256^-0.5
  }
  #pragma unroll
  for (int q = 0; q < 32; ++q) buf[q * 260 + t] = acc[q];   // bank-friendly: (4q+t)%32
  __syncthreads();

  // ---- per-(q, 32-ball chunk) local top2 + local expsum ----
  {
    const int q = t & 31, c = t >> 5;
    const float* rowp = buf + q * 260 + c * 32;
    float vals[32];
    #pragma unroll
    for (int j = 0; j < 8; ++j) {
      float4 f = ((const float4*)rowp)[j];
      vals[4 * j + 0] = f.x; vals[4 * j + 1] = f.y;
      vals[4 * j + 2] = f.z; vals[4 * j + 3] = f.w;
    }
    float v1 = -FLT_BIG, v2 = -FLT_BIG; int i1 = 0, i2 = 0;
    #pragma unroll
    for (int j = 0; j < 32; ++j) {
      float v = vals[j]; const int idx = c * 32 + j;
      if (better(v, idx, v1, i1)) { v2 = v1; i2 = i1; v1 = v; i1 = idx; }
      else if (better(v, idx, v2, i2)) { v2 = v; i2 = idx; }
    }
    float es = 0.f;
    #pragma unroll
    for (int j = 0; j < 32; ++j) es += __expf(vals[j] - v1);
    cand[q * 8 + c] = make_float4(v1, v2, __int_as_float(i1), __int_as_float(i2));
    cesum[q * 8 + c] = es;
  }
  __syncthreads();

  // ---- merge 8 chunks per query (threads 0..31) ----
  if (t < 32) {
    const int q = t;
    float4 c0 = cand[q * 8];
    float V1 = c0.x, V2 = c0.y;
    int I1 = __float_as_int(c0.z), I2 = __float_as_int(c0.w);
    #pragma unroll
    for (int c = 1; c < 8; ++c) {
      float4 cc = cand[q * 8 + c];
      float nv1 = cc.x, nv2 = cc.y;
      int ni1 = __float_as_int(cc.z), ni2 = __float_as_int(cc.w);
      if (better(nv1, ni1, V1, I1)) {
        if (better(V1, I1, nv2, ni2)) { V2 = V1; I2 = I1; } else { V2 = nv2; I2 = ni2; }
        V1 = nv1; I1 = ni1;
      } else if (better(nv1, ni1, V2, I2)) { V2 = nv1; I2 = ni1; }
    }
    float E = 0.f;
    #pragma unroll
    for (int c = 0; c < 8; ++c) E += cesum[q * 8 + c] * __expf(cand[q * 8 + c].x - V1);
    const float topv1 = 1.0f / E;
    const float topv2 = __expf(V2 - V1) / E;
    const int o1 = (topv1 > 1e-10f) ? I1 : -1;
    const int o2 = (topv2 > 1e-10f) ? I2 : -1;
    sel[h * 8192 + b * 32 + q] = make_int2(o1, o2);
  }
}

// one wave per (h, q) task; 64 gathered keys from the 2 selected balls
__global__ __launch_bounds__(256) void attn_kernel(const float* __restrict__ x,
                                                   const int2* __restrict__ sel,
                                                   float* __restrict__ out) {
  __shared__ float p_lds[4 * 64];
  const int lane = threadIdx.x & 63;
  const int widx = threadIdx.x >> 6;
  const int task = blockIdx.x * 4 + widx;   // h*8192 + q
  const int h = task >> 13;
  const int q = task & 8191;

  const int2 sv = sel[task];
  const int iA = sv.x, iB = sv.y;
  const int bA = iA < 0 ? 0 : iA;
  const int bB = iB < 0 ? 0 : iB;

  const int ro = lane >> 3;          // row within 8-row group
  const int o = lane & 7;            // 16B chunk within row-slice
  const float4 qf = *(const float4*)(x + q * 256 + h * 32 + o * 4);

  // ---- key dots: 8 lanes per row (16 segs/instr), partial dot in regs ----
  float dA[4], dB[4];
  #pragma unroll
  for (int i = 0; i < 4; ++i) {
    const float4 ka = *(const float4*)(x + (bA * 32 + i * 8 + ro) * 256 + h * 32 + o * 4);
    float a = qf.x * ka.x; a = fmaf(qf.y, ka.y, a); a = fmaf(qf.z, ka.z, a); a = fmaf(qf.w, ka.w, a);
    dA[i] = a;
    const float4 kb = *(const float4*)(x + (bB * 32 + i * 8 + ro) * 256 + h * 32 + o * 4);
    float bb = qf.x * kb.x; bb = fmaf(qf.y, kb.y, bb); bb = fmaf(qf.z, kb.z, bb); bb = fmaf(qf.w, kb.w, bb);
    dB[i] = bb;
  }
  // finish dots across the 8 o-lanes (rows identical within each group)
  #pragma unroll
  for (int m = 1; m <= 4; m <<= 1) {
    #pragma unroll
    for (int i = 0; i < 4; ++i) {
      dA[i] += __shfl_xor(dA[i], m);
      dB[i] += __shfl_xor(dB[i], m);
    }
  }

  // ---- masked softmax over 64 slots (values replicated 8x across o-lanes) ----
  float lA[4], lB[4];
  float mx = -FLT_BIG;
  #pragma unroll
  for (int i = 0; i < 4; ++i) {
    lA[i] = (iA >= 0) ? dA[i] * 0.0625f : -FLT_BIG;
    lB[i] = (iB >= 0) ? dB[i] * 0.0625f : -FLT_BIG;
    mx = fmaxf(mx, fmaxf(lA[i], lB[i]));
  }
  #pragma unroll
  for (int m = 8; m <= 32; m <<= 1) mx = fmaxf(mx, __shfl_xor(mx, m));
  float pA[4], pB[4], psum = 0.f;
  #pragma unroll
  for (int i = 0; i < 4; ++i) {
    pA[i] = __expf(lA[i] - mx);
    pB[i] = __expf(lB[i] - mx);
    psum += pA[i] + pB[i];
  }
  // rows counted once: reduce only across ro (bits 3..5); o-lanes are replicas
  #pragma unroll
  for (int m = 8; m <= 32; m <<= 1) psum += __shfl_xor(psum, m);

  // ---- stash p to LDS (one writer lane per row) ----
  const int wbase = widx * 64;
  #pragma unroll
  for (int i = 0; i < 4; ++i) {
    if ((lane & 7) == i) {
      p_lds[wbase + 8 * i + ro] = pA[i];
      p_lds[wbase + 32 + 8 * i + ro] = pB[i];
    }
  }

  // ---- PV: lane (t2,e) sums 32 rows of its ball; V re-read transposed (L1-hot) ----
  const int t2 = lane >> 5;
  const int e = lane & 31;
  const int bP = t2 ? bB : bA;
  const float* vp = x + bP * 32 * 256 + h * 32 + e;
  float acc = 0.f;
  #pragma unroll
  for (int s = 0; s < 32; ++s) {
    float w = p_lds[wbase + t2 * 32 + s];   // broadcast read
    acc = fmaf(w, vp[s * 256], acc);
  }
  acc += __shfl_xor(acc, 32);
  if (lane < 32) out[q * 256 + h * 32 + e] = acc / psum;
}

extern "C" void kernel_launch(void* const* d_in, const int* in_sizes, int n_in,
                              void* d_out, int out_size, void* d_ws, size_t ws_size,
                              hipStream_t stream) {
  const float* x = (const float*)d_in[0];   // (8192, 256) fp32; pos (d_in[1]) is dead code
  float* km = (float*)d_ws;                                  // 256 KB
  int2* sel = (int2*)((char*)d_ws + 8 * 8192 * sizeof(float)); // 512 KB
  float* out = (float*)d_out;

  kmean_kernel<<<256, 256, 0, stream>>>(x, km);
  select_kernel<<<2048, 256, 0, stream>>>(x, km, sel);
  attn_kernel<<<16384, 256, 0, stream>>>(x, sel, out);
}

// Round 3
// 80.032 us; speedup vs baseline: 4.2239x; 1.1050x over previous
//
#include <hip/hip_runtime.h>

#define FLT_BIG 3.402823466e38f

// tie-break matches jax.lax.top_k: higher value wins; equal values -> lower index wins
static __device__ __forceinline__ bool better(float v1, int i1, float v2, int i2) {
  return (v1 > v2) || ((v1 == v2) && (i1 < i2));
}

// km[h][n][e] = mean_j x[(n*32+j)*256 + h*32+e]
__global__ void kmean_kernel(const float* __restrict__ x, float* __restrict__ km) {
  const int n = blockIdx.x;        // ball
  const int t = threadIdx.x;       // h*32+e
  const float* base = x + n * 32 * 256 + t;
  float acc = 0.f;
  #pragma unroll
  for (int j = 0; j < 32; ++j) acc += base[j * 256];
  const int h = t >> 5, e = t & 31;
  km[h * 8192 + n * 32 + e] = acc * (1.0f / 32.0f);
}

// Register-tiled sim GEMM + top2 + expsum.
// Block = (head h, 64-query group). Thread tile = 8q x 8balls (balls tb+32j).
__global__ __launch_bounds__(256) void select_kernel(const float* __restrict__ x,
                                                     const float* __restrict__ km,
                                                     int2* __restrict__ sel) {
  // union: GEMM phase uses [0,10240) = km(8192) + q(2048); merge phase uses [0,11840)
  __shared__ float smem[11840];
  const int h = blockIdx.x >> 7;    // blocks with same head contiguous -> L2 reuse of km[h]
  const int qb = blockIdx.x & 127;  // 64-query group
  const int t = threadIdx.x;
  const int tq = t >> 5;            // q-group 0..7 (8 rows each)
  const int tb = t & 31;            // ball-group 0..31 (balls tb+32j)

  float* km_l = smem;               // 256 balls x 8 float4-chunks, chunk XOR-swizzled
  float* q_l = smem + 8192;         // 64 rows x 32 floats

  // ---- stage km[h] (chunk c of ball b stored at slot c ^ (b&7)) ----
  {
    const float4* src = (const float4*)(km + h * 8192);
    float4* dst = (float4*)km_l;
    #pragma unroll
    for (int k = 0; k < 8; ++k) {
      const int idx = t + 256 * k;          // float4 index 0..2047
      const float4 v = src[idx];
      const int ball = idx >> 3, c = idx & 7;
      dst[ball * 8 + (c ^ (ball & 7))] = v;
    }
  }
  // ---- stage q rows (coalesced: 8 lanes per row) ----
  {
    float4* dst = (float4*)q_l;
    #pragma unroll
    for (int k = 0; k < 2; ++k) {
      const int idx = t + 256 * k;          // 0..511
      const int r = idx >> 3, c = idx & 7;
      dst[idx] = *(const float4*)(x + (qb * 64 + r) * 256 + h * 32 + c * 4);
    }
  }
  __syncthreads();

  // ---- GEMM: acc[i][j] = q[8tq+i] . km[tb+32j] ----
  float acc[8][8];
  #pragma unroll
  for (int i = 0; i < 8; ++i)
    #pragma unroll
    for (int j = 0; j < 8; ++j) acc[i][j] = 0.f;

  const float4* q4 = (const float4*)q_l;
  const float4* k4 = (const float4*)km_l;
  const int swz = tb & 7;
  #pragma unroll
  for (int s = 0; s < 8; ++s) {
    float4 qf[8], kf[8];
    #pragma unroll
    for (int i = 0; i < 8; ++i) qf[i] = q4[(8 * tq + i) * 8 + s];
    #pragma unroll
    for (int j = 0; j < 8; ++j) kf[j] = k4[(tb + 32 * j) * 8 + (s ^ swz)];
    #pragma unroll
    for (int i = 0; i < 8; ++i)
      #pragma unroll
      for (int j = 0; j < 8; ++j) {
        acc[i][j] = fmaf(qf[i].x, kf[j].x, acc[i][j]);
        acc[i][j] = fmaf(qf[i].y, kf[j].y, acc[i][j]);
        acc[i][j] = fmaf(qf[i].z, kf[j].z, acc[i][j]);
        acc[i][j] = fmaf(qf[i].w, kf[j].w, acc[i][j]);
      }
  }
  __syncthreads();   // done reading km_l/q_l; smem is reused below

  // merge arrays (stride-33 rows -> conflict-free row-direction reads)
  float* c_v1 = smem;
  float* c_v2 = smem + 2112;
  float* c_i1 = smem + 4224;
  float* c_i2 = smem + 6336;
  float* c_es = smem + 8448;        // ends at 10560
  float* s_v1 = smem + 10560;       // 64 rows x 4 chunks
  float* s_v2 = smem + 10816;
  float* s_i1 = smem + 11072;
  float* s_i2 = smem + 11328;
  float* s_es = smem + 11584;       // ends at 11840

  // ---- per-thread top2 + expsum over its 8 balls, per q-row ----
  #pragma unroll
  for (int i = 0; i < 8; ++i) {
    const int r = 8 * tq + i;
    float v1 = acc[i][0] * 0.0625f; int i1 = tb;   // scale = 256^-0.5
    float v2 = -FLT_BIG; int i2 = 0x7fffffff;
    #pragma unroll
    for (int j = 1; j < 8; ++j) {
      const float v = acc[i][j] * 0.0625f; const int idx = tb + 32 * j;
      if (better(v, idx, v1, i1)) { v2 = v1; i2 = i1; v1 = v; i1 = idx; }
      else if (better(v, idx, v2, i2)) { v2 = v; i2 = idx; }
    }
    float es = 0.f;
    #pragma unroll
    for (int j = 0; j < 8; ++j) es += __expf(acc[i][j] * 0.0625f - v1);
    c_v1[r * 33 + tb] = v1;
    c_v2[r * 33 + tb] = v2;
    c_i1[r * 33 + tb] = __int_as_float(i1);
    c_i2[r * 33 + tb] = __int_as_float(i2);
    c_es[r * 33 + tb] = es;
  }
  __syncthreads();

  // ---- level-1 merge: thread (r = t&63, c = t>>6) merges tb = 8c..8c+7 ----
  {
    const int r = t & 63, c = t >> 6;
    const int base = r * 33 + c * 8;
    float V1 = c_v1[base], V2 = c_v2[base];
    int I1 = __float_as_int(c_i1[base]), I2 = __float_as_int(c_i2[base]);
    float E = c_es[base];
    #pragma unroll
    for (int k = 1; k < 8; ++k) {
      const float nv1 = c_v1[base + k], nv2 = c_v2[base + k], nes = c_es[base + k];
      const int ni1 = __float_as_int(c_i1[base + k]), ni2 = __float_as_int(c_i2[base + k]);
      const float m = fmaxf(V1, nv1);
      E = E * __expf(V1 - m) + nes * __expf(nv1 - m);
      if (better(nv1, ni1, V1, I1)) {
        if (better(V1, I1, nv2, ni2)) { V2 = V1; I2 = I1; } else { V2 = nv2; I2 = ni2; }
        V1 = nv1; I1 = ni1;
      } else if (better(nv1, ni1, V2, I2)) { V2 = nv1; I2 = ni1; }
    }
    s_v1[r * 4 + c] = V1; s_v2[r * 4 + c] = V2;
    s_i1[r * 4 + c] = __int_as_float(I1); s_i2[r * 4 + c] = __int_as_float(I2);
    s_es[r * 4 + c] = E;
  }
  __syncthreads();

  // ---- level-2 merge + emit (one thread per q-row) ----
  if (t < 64) {
    const int r = t;
    float V1 = s_v1[r * 4], V2 = s_v2[r * 4];
    int I1 = __float_as_int(s_i1[r * 4]), I2 = __float_as_int(s_i2[r * 4]);
    float E = s_es[r * 4];
    #pragma unroll
    for (int c = 1; c < 4; ++c) {
      const float nv1 = s_v1[r * 4 + c], nv2 = s_v2[r * 4 + c], nes = s_es[r * 4 + c];
      const int ni1 = __float_as_int(s_i1[r * 4 + c]), ni2 = __float_as_int(s_i2[r * 4 + c]);
      const float m = fmaxf(V1, nv1);
      E = E * __expf(V1 - m) + nes * __expf(nv1 - m);
      if (better(nv1, ni1, V1, I1)) {
        if (better(V1, I1, nv2, ni2)) { V2 = V1; I2 = I1; } else { V2 = nv2; I2 = ni2; }
        V1 = nv1; I1 = ni1;
      } else if (better(nv1, ni1, V2, I2)) { V2 = nv1; I2 = ni1; }
    }
    const float topv1 = 1.0f / E;
    const float topv2 = __expf(V2 - V1) / E;
    const int o1 = (topv1 > 1e-10f) ? I1 : -1;
    const int o2 = (topv2 > 1e-10f) ? I2 : -1;
    sel[h * 8192 + qb * 64 + r] = make_int2(o1, o2);
  }
}

// one wave per (h, q) task; 64 gathered keys from the 2 selected balls
__global__ __launch_bounds__(256) void attn_kernel(const float* __restrict__ x,
                                                   const int2* __restrict__ sel,
                                                   float* __restrict__ out) {
  __shared__ float p_lds[4 * 64];
  const int lane = threadIdx.x & 63;
  const int widx = threadIdx.x >> 6;
  const int task = blockIdx.x * 4 + widx;   // h*8192 + q
  const int h = task >> 13;
  const int q = task & 8191;

  const int2 sv = sel[task];
  const int iA = sv.x, iB = sv.y;
  const int bA = iA < 0 ? 0 : iA;
  const int bB = iB < 0 ? 0 : iB;

  const int ro = lane >> 3;          // row within 8-row group
  const int o = lane & 7;            // 16B chunk within row-slice
  const float4 qf = *(const float4*)(x + q * 256 + h * 32 + o * 4);

  // ---- key dots: 8 lanes per row (8 x 128B segments/instr) ----
  float dA[4], dB[4];
  #pragma unroll
  for (int i = 0; i < 4; ++i) {
    const float4 ka = *(const float4*)(x + (bA * 32 + i * 8 + ro) * 256 + h * 32 + o * 4);
    float a = qf.x * ka.x; a = fmaf(qf.y, ka.y, a); a = fmaf(qf.z, ka.z, a); a = fmaf(qf.w, ka.w, a);
    dA[i] = a;
    const float4 kb = *(const float4*)(x + (bB * 32 + i * 8 + ro) * 256 + h * 32 + o * 4);
    float bb = qf.x * kb.x; bb = fmaf(qf.y, kb.y, bb); bb = fmaf(qf.z, kb.z, bb); bb = fmaf(qf.w, kb.w, bb);
    dB[i] = bb;
  }
  #pragma unroll
  for (int m = 1; m <= 4; m <<= 1) {
    #pragma unroll
    for (int i = 0; i < 4; ++i) {
      dA[i] += __shfl_xor(dA[i], m);
      dB[i] += __shfl_xor(dB[i], m);
    }
  }

  // ---- masked softmax over 64 slots (values replicated 8x across o-lanes) ----
  float lA[4], lB[4];
  float mx = -FLT_BIG;
  #pragma unroll
  for (int i = 0; i < 4; ++i) {
    lA[i] = (iA >= 0) ? dA[i] * 0.0625f : -FLT_BIG;
    lB[i] = (iB >= 0) ? dB[i] * 0.0625f : -FLT_BIG;
    mx = fmaxf(mx, fmaxf(lA[i], lB[i]));
  }
  #pragma unroll
  for (int m = 8; m <= 32; m <<= 1) mx = fmaxf(mx, __shfl_xor(mx, m));
  float pA[4], pB[4], psum = 0.f;
  #pragma unroll
  for (int i = 0; i < 4; ++i) {
    pA[i] = __expf(lA[i] - mx);
    pB[i] = __expf(lB[i] - mx);
    psum += pA[i] + pB[i];
  }
  #pragma unroll
  for (int m = 8; m <= 32; m <<= 1) psum += __shfl_xor(psum, m);

  // ---- stash p to LDS (one writer lane per row) ----
  const int wbase = widx * 64;
  #pragma unroll
  for (int i = 0; i < 4; ++i) {
    if ((lane & 7) == i) {
      p_lds[wbase + 8 * i + ro] = pA[i];
      p_lds[wbase + 32 + 8 * i + ro] = pB[i];
    }
  }

  // ---- PV: lane (t2,e) sums 32 rows of its ball; V re-read transposed (L1-hot) ----
  const int t2 = lane >> 5;
  const int e = lane & 31;
  const int bP = t2 ? bB : bA;
  const float* vp = x + bP * 32 * 256 + h * 32 + e;
  float acc = 0.f;
  #pragma unroll
  for (int s = 0; s < 32; ++s) {
    float w = p_lds[wbase + t2 * 32 + s];   // broadcast read
    acc = fmaf(w, vp[s * 256], acc);
  }
  acc += __shfl_xor(acc, 32);
  if (lane < 32) out[q * 256 + h * 32 + e] = acc / psum;
}

extern "C" void kernel_launch(void* const* d_in, const int* in_sizes, int n_in,
                              void* d_out, int out_size, void* d_ws, size_t ws_size,
                              hipStream_t stream) {
  const float* x = (const float*)d_in[0];   // (8192, 256) fp32; pos (d_in[1]) is dead code
  float* km = (float*)d_ws;                                    // 256 KB
  int2* sel = (int2*)((char*)d_ws + 8 * 8192 * sizeof(float)); // 512 KB
  float* out = (float*)d_out;

  kmean_kernel<<<256, 256, 0, stream>>>(x, km);
  select_kernel<<<1024, 256, 0, stream>>>(x, km, sel);
  attn_kernel<<<16384, 256, 0, stream>>>(x, sel, out);
}